// Round 15
// baseline (393.543 us; speedup 1.0000x reference)
//
#include <hip/hip_runtime.h>

// ---------------------------------------------------------------------------
// AttentionCritic on MI355X — round 15: r14 + TRUE counted-vmcnt (T4) DOT GEMM:
// 3-buffer LDS pipeline (BM=256,BN=128,BK=64; 144KB), vmcnt(6) waits on loads
// issued TWO tiles earlier while next tile's 6 loads stay in flight.
// Fallback to proven dot2_k if 144KB dyn-LDS opt-in is denied.
// ---------------------------------------------------------------------------

#define DEVI __device__ __forceinline__

typedef unsigned short us16;
typedef __bf16 bf16x8 __attribute__((ext_vector_type(8)));
typedef float f32x4 __attribute__((ext_vector_type(4)));
typedef unsigned short u16x8 __attribute__((ext_vector_type(8)));

DEVI us16 f2bf(float f) {
  unsigned u = __builtin_bit_cast(unsigned, f);
  u += 0x7FFFu + ((u >> 16) & 1u);          // round-to-nearest-even
  return (us16)(u >> 16);
}
DEVI float bf2f(us16 h) {
  unsigned u = ((unsigned)h) << 16;
  return __builtin_bit_cast(float, u);
}
DEVI float lrelu(float v) { return v > 0.f ? v : 0.01f * v; }
DEVI int pk2(float a, float b) { return (int)f2bf(a) | ((int)f2bf(b) << 16); }

// async global->LDS, 16B per lane. LDS dest must be linear: base + lane*16.
DEVI void gload16(const us16* g, us16* l) {
  __builtin_amdgcn_global_load_lds(
      (const __attribute__((address_space(1))) void*)g,
      (__attribute__((address_space(3))) void*)l, 16, 0, 0);
}

// ---------------------------------------------------------------------------
// Transposes (fp32 -> bf16, [K][O] -> [O][Kpad])
// ---------------------------------------------------------------------------
__global__ void tconvSA_k(const float* __restrict__ wsrc, const float* __restrict__ wsasrc,
                          us16* __restrict__ wst, us16* __restrict__ wsat)
{
  __shared__ float t[32][33];
  const int zz = blockIdx.z;               // 0..15
  const int m = zz >> 3, s = zz & 7;
  const int K = m ? 80 : 64, Kpad = m ? 96 : 64;
  const float* src = m ? (wsasrc + (long)s * 80 * 512) : (wsrc + (long)s * 64 * 512);
  us16* dst = m ? (wsat + (long)s * 512 * 96) : (wst + (long)s * 512 * 64);
  const int k0 = blockIdx.x * 32, o0 = blockIdx.y * 32;
  const int lx = threadIdx.x, ly = threadIdx.y;
#pragma unroll
  for (int i = 0; i < 4; i++) {
    int k = k0 + ly + i * 8, o = o0 + lx;
    float v = 0.f;
    if (k < K) v = src[(long)k * 512 + o];
    t[ly + i * 8][lx] = v;
  }
  __syncthreads();
#pragma unroll
  for (int i = 0; i < 4; i++) {
    int o = o0 + ly + i * 8, k = k0 + lx;
    if (k < Kpad)
      dst[(long)o * Kpad + k] = f2bf(t[lx][ly + i * 8]);
  }
}

__global__ void tconv3_k(const float* __restrict__ wk, const float* __restrict__ wsel,
                         const float* __restrict__ wv, us16* __restrict__ dst)
{
  __shared__ float t[32][33];
  const int zz = blockIdx.z;               // 0..11
  const int e = zz & 3, m = zz >> 2;       // m: 0=key 1=sel 2=val
  const float* src = ((m == 0) ? wk : (m == 1) ? wsel : wv) + (long)e * 512 * 128;
  us16* d = dst + (long)e * 384 * 512 + (long)(m * 128) * 512;
  const int k0 = blockIdx.x * 32, o0 = blockIdx.y * 32;
  const int lx = threadIdx.x, ly = threadIdx.y;
#pragma unroll
  for (int i = 0; i < 4; i++)
    t[ly + i * 8][lx] = src[(long)(k0 + ly + i * 8) * 128 + (o0 + lx)];
  __syncthreads();
#pragma unroll
  for (int i = 0; i < 4; i++)
    d[(long)(o0 + ly + i * 8) * 512 + (k0 + lx)] = f2bf(t[lx][ly + i * 8]);
}

__global__ void tconvC_k(const float* __restrict__ c1, const float* __restrict__ v1,
                         us16* __restrict__ dc, us16* __restrict__ dv)
{
  __shared__ float t[32][33];
  const int zz = blockIdx.z;               // 0..15
  const int n = zz & 7, m = zz >> 3;
  const float* src = ((m == 0) ? c1 : v1) + (long)n * 1024 * 512;
  us16* dst = ((m == 0) ? dc : dv) + (long)n * 512 * 1024;
  const int k0 = blockIdx.x * 32, o0 = blockIdx.y * 32;
  const int lx = threadIdx.x, ly = threadIdx.y;
#pragma unroll
  for (int i = 0; i < 4; i++)
    t[ly + i * 8][lx] = src[(long)(k0 + ly + i * 8) * 512 + (o0 + lx)];
  __syncthreads();
#pragma unroll
  for (int i = 0; i < 4; i++)
    dst[(long)(o0 + ly + i * 8) * 1024 + (k0 + lx)] = f2bf(t[lx][ly + i * 8]);
}

// ---------------------------------------------------------------------------
// fp32-input encoder GEMM (proven, BK=32, linear LDS).
// ---------------------------------------------------------------------------
enum { ASRC_F32 = 2, ASRC_F32_CAT = 3 };

template <int ASRC, int KTOT>
__global__ __launch_bounds__(256, 4)
void enc_gemm_k(const float* __restrict__ Ap, long aSlice,
                const float* __restrict__ A2p, long a2Slice,
                const us16* __restrict__ Btp, long bSlice,
                const float* __restrict__ bias, long biasSlice,
                us16* __restrict__ outB, long outSlice, long outRow)
{
  __shared__ us16 lA[128 * 32];
  __shared__ us16 lB[128 * 32];
  const int tid = threadIdx.x;
  const int z = blockIdx.z;
  const int m0 = blockIdx.x * 128;
  const int n0 = blockIdx.y * 128;
  const int wv = tid >> 6, lane = tid & 63;
  const int wm = (wv >> 1) * 64, wn = (wv & 1) * 64;
  const int fr = lane & 15, fk = (lane >> 4) * 8;
  const int rbase = (lane >> 4) * 4;
  const int grow = tid >> 2, gcol = (tid & 3) * 8;

  f32x4 acc[4][4];
#pragma unroll
  for (int i = 0; i < 4; i++)
#pragma unroll
    for (int j = 0; j < 4; j++) acc[i][j] = f32x4{0.f, 0.f, 0.f, 0.f};

  const us16* bbase = Btp + (long)z * bSlice + (long)n0 * KTOT;

  for (int k0 = 0; k0 < KTOT; k0 += 32) {
    int4 ra0, ra1;
    {
      const int srow = tid >> 1, scol0 = (tid & 1) * 16;
      const int kg = k0 + scol0;
      const float* a = nullptr;
      if constexpr (ASRC == ASRC_F32) {
        a = Ap + (long)z * aSlice + (long)(m0 + srow) * 64 + kg;
      } else {  // states(0..63) | actions(64..79) | zero pad(80..95)
        if (kg < 64)      a = Ap + (long)z * aSlice + (long)(m0 + srow) * 64 + kg;
        else if (kg < 80) a = A2p + (long)z * a2Slice + (long)(m0 + srow) * 16 + (kg - 64);
      }
      float4 f0, f1, f2, f3;
      if (a) { const float4* ap = (const float4*)a; f0 = ap[0]; f1 = ap[1]; f2 = ap[2]; f3 = ap[3]; }
      else   { f0 = make_float4(0.f, 0.f, 0.f, 0.f); f1 = f0; f2 = f0; f3 = f0; }
      ra0.x = pk2(f0.x, f0.y); ra0.y = pk2(f0.z, f0.w); ra0.z = pk2(f1.x, f1.y); ra0.w = pk2(f1.z, f1.w);
      ra1.x = pk2(f2.x, f2.y); ra1.y = pk2(f2.z, f2.w); ra1.z = pk2(f3.x, f3.y); ra1.w = pk2(f3.z, f3.w);
    }

    __syncthreads();
    {
      const us16* bb = bbase + k0 + gcol;
      gload16(bb + (long)grow * KTOT, &lB[tid * 8]);
      gload16(bb + (long)(64 + grow) * KTOT, &lB[2048 + tid * 8]);
    }
    {
      const int srow = tid >> 1, scol0 = (tid & 1) * 16;
      *(int4*)&lA[srow * 32 + scol0]     = ra0;
      *(int4*)&lA[srow * 32 + scol0 + 8] = ra1;
    }
    __syncthreads();

    bf16x8 af[4], bfg[4];
#pragma unroll
    for (int f = 0; f < 4; f++) af[f]  = *(const bf16x8*)&lA[(wm + f * 16 + fr) * 32 + fk];
#pragma unroll
    for (int f = 0; f < 4; f++) bfg[f] = *(const bf16x8*)&lB[(wn + f * 16 + fr) * 32 + fk];
#pragma unroll
    for (int fm = 0; fm < 4; fm++)
#pragma unroll
      for (int fn = 0; fn < 4; fn++)
        acc[fm][fn] = __builtin_amdgcn_mfma_f32_16x16x32_bf16(af[fm], bfg[fn], acc[fm][fn], 0, 0, 0);
  }

#pragma unroll
  for (int fm = 0; fm < 4; fm++) {
#pragma unroll
    for (int fn = 0; fn < 4; fn++) {
      int col = n0 + wn + fn * 16 + fr;
      float badd = bias[(long)z * biasSlice + col];
      us16* op = outB + (long)z * outSlice + (long)(m0 + wm + fm * 16 + rbase) * outRow + col;
#pragma unroll
      for (int j = 0; j < 4; j++) {
        float v = lrelu(acc[fm][fn][j] + badd);
        op[(long)j * outRow] = f2bf(v);
      }
    }
  }
}

// ---------------------------------------------------------------------------
// Proven 128^2 bf16 GEMM (BK=64, XOR-swizzle, 2-barrier) — Tier B forms.
// ---------------------------------------------------------------------------
enum { EPI_KSV = 1, EPI_DOT = 2 };

template <bool CAT, int EPI, int KTOT>
__global__ __launch_bounds__(256, 4)
void gemm64_k(const us16* __restrict__ Ap, long aSlice,
              const us16* __restrict__ A2p, long a2Slice,
              const us16* __restrict__ Btp, long bSlice,
              const float* __restrict__ bias,
              us16* __restrict__ outB, long outSlice, long outRow,
              const float* __restrict__ dotW, float* __restrict__ partial)
{
  __shared__ us16 lA[128 * 64];
  __shared__ us16 lB[128 * 64];
  const int tid = threadIdx.x;
  const int z = blockIdx.z;
  const int m0 = blockIdx.x * 128;
  const int n0 = blockIdx.y * 128;
  const int wv = tid >> 6, lane = tid & 63;
  const int wm = (wv >> 1) * 64, wn = (wv & 1) * 64;
  const int fr = lane & 15, fk = (lane >> 4) * 8;
  const int rbase = (lane >> 4) * 4;
  const int xorkey = (fr & 7) << 3;

  f32x4 acc[4][4];
#pragma unroll
  for (int i = 0; i < 4; i++)
#pragma unroll
    for (int j = 0; j < 4; j++) acc[i][j] = f32x4{0.f, 0.f, 0.f, 0.f};

  const us16* bbase = Btp + (long)z * bSlice + (long)n0 * KTOT;

  for (int k0 = 0; k0 < KTOT; k0 += 64) {
    __syncthreads();
#pragma unroll
    for (int i = 0; i < 4; i++) {
      const int c = i * 256 + tid;
      const int r = c >> 3;
      const int col = ((c & 7) ^ (r & 7)) << 3;
      const us16* a;
      if constexpr (!CAT) {
        a = Ap + (long)z * aSlice + (long)(m0 + r) * KTOT + (k0 + col);
      } else {
        const int kg = k0 + col;
        a = (kg < 512) ? Ap  + (long)z * aSlice  + (long)(m0 + r) * 512 + kg
                       : A2p + (long)z * a2Slice + (long)(m0 + r) * 512 + (kg - 512);
      }
      gload16(a, &lA[c * 8]);
    }
#pragma unroll
    for (int i = 0; i < 4; i++) {
      const int c = i * 256 + tid;
      const int r = c >> 3;
      const int col = ((c & 7) ^ (r & 7)) << 3;
      gload16(bbase + (long)r * KTOT + (k0 + col), &lB[c * 8]);
    }
    __syncthreads();

#pragma unroll
    for (int ks = 0; ks < 2; ks++) {
      bf16x8 af[4], bfg[4];
      const int kc = ks * 32 + fk;
#pragma unroll
      for (int f = 0; f < 4; f++)
        af[f]  = *(const bf16x8*)&lA[(wm + f * 16 + fr) * 64 + (kc ^ xorkey)];
#pragma unroll
      for (int f = 0; f < 4; f++)
        bfg[f] = *(const bf16x8*)&lB[(wn + f * 16 + fr) * 64 + (kc ^ xorkey)];
#pragma unroll
      for (int fm = 0; fm < 4; fm++)
#pragma unroll
        for (int fn = 0; fn < 4; fn++)
          acc[fm][fn] = __builtin_amdgcn_mfma_f32_16x16x32_bf16(af[fm], bfg[fn], acc[fm][fn], 0, 0, 0);
    }
  }

  if constexpr (EPI == EPI_DOT) {
    const float* bsl = bias + (long)z * 512;
    const float* wsl = dotW + (long)z * 512;
#pragma unroll
    for (int fm = 0; fm < 4; fm++) {
#pragma unroll
      for (int j = 0; j < 4; j++) {
        float p = 0.f;
#pragma unroll
        for (int fn = 0; fn < 4; fn++) {
          int col = n0 + wn + fn * 16 + fr;
          float v = acc[fm][fn][j] + bsl[col];
          v = lrelu(v);
          p += v * wsl[col];
        }
        p += __shfl_xor(p, 1); p += __shfl_xor(p, 2); p += __shfl_xor(p, 4); p += __shfl_xor(p, 8);
        if (fr == 0) {
          long row = (long)z * 8192 + (m0 + wm + fm * 16 + rbase + j);
          partial[row * 8 + blockIdx.y * 2 + (wv & 1)] = p;
        }
      }
    }
  } else {
#pragma unroll
    for (int fm = 0; fm < 4; fm++) {
#pragma unroll
      for (int fn = 0; fn < 4; fn++) {
        int col = n0 + wn + fn * 16 + fr;
        float badd = 0.f; bool act = false;
        if (col >= 256) { badd = bias[col - 256]; act = true; }
        us16* op = outB + (long)z * outSlice + (long)(m0 + wm + fm * 16 + rbase) * outRow + col;
#pragma unroll
        for (int j = 0; j < 4; j++) {
          float v = acc[fm][fn][j] + badd;
          if (act) v = lrelu(v);
          op[(long)j * outRow] = f2bf(v);
        }
      }
    }
  }
}

// ---------------------------------------------------------------------------
// Tier A2: 2-head fused KSV GEMM (proven round-10).
// ---------------------------------------------------------------------------
__global__ __launch_bounds__(256, 4)
void ksv2_k(const us16* __restrict__ enc, const us16* __restrict__ wkvst2,
            const float* __restrict__ bv2h, us16* __restrict__ ksv2)
{
  __shared__ us16 lA[128 * 64];
  __shared__ us16 lB[128 * 64];
  constexpr int KTOT = 512;
  const int tid = threadIdx.x;
  const int z = blockIdx.z;                    // agent
  const int el = blockIdx.y / 3;               // head within pair
  const int n0 = (blockIdx.y % 3) * 128;
  const int m0 = blockIdx.x * 128;
  const int wv = tid >> 6, lane = tid & 63;
  const int wm = (wv >> 1) * 64, wn = (wv & 1) * 64;
  const int fr = lane & 15, fk = (lane >> 4) * 8;
  const int rbase = (lane >> 4) * 4;
  const int xorkey = (fr & 7) << 3;

  f32x4 acc[4][4];
#pragma unroll
  for (int i = 0; i < 4; i++)
#pragma unroll
    for (int j = 0; j < 4; j++) acc[i][j] = f32x4{0.f, 0.f, 0.f, 0.f};

  const us16* abase = enc + (long)z * 8192 * 512 + (long)m0 * KTOT;
  const us16* bbase = wkvst2 + ((long)el * 384 + n0) * KTOT;

  for (int k0 = 0; k0 < KTOT; k0 += 64) {
    __syncthreads();
#pragma unroll
    for (int i = 0; i < 4; i++) {
      const int c = i * 256 + tid;
      const int r = c >> 3;
      const int col = ((c & 7) ^ (r & 7)) << 3;
      gload16(abase + (long)r * KTOT + (k0 + col), &lA[c * 8]);
    }
#pragma unroll
    for (int i = 0; i < 4; i++) {
      const int c = i * 256 + tid;
      const int r = c >> 3;
      const int col = ((c & 7) ^ (r & 7)) << 3;
      gload16(bbase + (long)r * KTOT + (k0 + col), &lB[c * 8]);
    }
    __syncthreads();

#pragma unroll
    for (int ks = 0; ks < 2; ks++) {
      bf16x8 af[4], bfg[4];
      const int kc = ks * 32 + fk;
#pragma unroll
      for (int f = 0; f < 4; f++)
        af[f]  = *(const bf16x8*)&lA[(wm + f * 16 + fr) * 64 + (kc ^ xorkey)];
#pragma unroll
      for (int f = 0; f < 4; f++)
        bfg[f] = *(const bf16x8*)&lB[(wn + f * 16 + fr) * 64 + (kc ^ xorkey)];
#pragma unroll
      for (int fm = 0; fm < 4; fm++)
#pragma unroll
        for (int fn = 0; fn < 4; fn++)
          acc[fm][fn] = __builtin_amdgcn_mfma_f32_16x16x32_bf16(af[fm], bfg[fn], acc[fm][fn], 0, 0, 0);
    }
  }

#pragma unroll
  for (int fm = 0; fm < 4; fm++) {
#pragma unroll
    for (int fn = 0; fn < 4; fn++) {
      int col = n0 + wn + fn * 16 + fr;          // 0..383 within head
      float badd = 0.f; bool act = false;
      if (col >= 256) { badd = bv2h[el * 128 + (col - 256)]; act = true; }
      us16* op = ksv2 + (long)(m0 + wm + fm * 16 + rbase) * 6144 + el * 3072 + z * 384 + col;
#pragma unroll
      for (int j = 0; j < 4; j++) {
        float v = acc[fm][fn][j] + badd;
        if (act) v = lrelu(v);
        op[(long)j * 6144] = f2bf(v);
      }
    }
  }
}

// ---------------------------------------------------------------------------
// Tier A4: 4-head fused KSV GEMM. grid (64, 12, 8): e = by/3, n0 = (by%3)*128.
// ---------------------------------------------------------------------------
__global__ __launch_bounds__(256, 4)
void ksv4_k(const us16* __restrict__ enc, const us16* __restrict__ wkvst,
            const float* __restrict__ bv, us16* __restrict__ ksv4)
{
  __shared__ us16 lA[128 * 64];
  __shared__ us16 lB[128 * 64];
  constexpr int KTOT = 512;
  const int tid = threadIdx.x;
  const int z = blockIdx.z;                    // agent
  const int e = blockIdx.y / 3;
  const int n0 = (blockIdx.y % 3) * 128;
  const int m0 = blockIdx.x * 128;
  const int wv = tid >> 6, lane = tid & 63;
  const int wm = (wv >> 1) * 64, wn = (wv & 1) * 64;
  const int fr = lane & 15, fk = (lane >> 4) * 8;
  const int rbase = (lane >> 4) * 4;
  const int xorkey = (fr & 7) << 3;

  f32x4 acc[4][4];
#pragma unroll
  for (int i = 0; i < 4; i++)
#pragma unroll
    for (int j = 0; j < 4; j++) acc[i][j] = f32x4{0.f, 0.f, 0.f, 0.f};

  const us16* abase = enc + (long)z * 8192 * 512 + (long)m0 * KTOT;
  const us16* bbase = wkvst + ((long)e * 384 + n0) * KTOT;

  for (int k0 = 0; k0 < KTOT; k0 += 64) {
    __syncthreads();
#pragma unroll
    for (int i = 0; i < 4; i++) {
      const int c = i * 256 + tid;
      const int r = c >> 3;
      const int col = ((c & 7) ^ (r & 7)) << 3;
      gload16(abase + (long)r * KTOT + (k0 + col), &lA[c * 8]);
    }
#pragma unroll
    for (int i = 0; i < 4; i++) {
      const int c = i * 256 + tid;
      const int r = c >> 3;
      const int col = ((c & 7) ^ (r & 7)) << 3;
      gload16(bbase + (long)r * KTOT + (k0 + col), &lB[c * 8]);
    }
    __syncthreads();

#pragma unroll
    for (int ks = 0; ks < 2; ks++) {
      bf16x8 af[4], bfg[4];
      const int kc = ks * 32 + fk;
#pragma unroll
      for (int f = 0; f < 4; f++)
        af[f]  = *(const bf16x8*)&lA[(wm + f * 16 + fr) * 64 + (kc ^ xorkey)];
#pragma unroll
      for (int f = 0; f < 4; f++)
        bfg[f] = *(const bf16x8*)&lB[(wn + f * 16 + fr) * 64 + (kc ^ xorkey)];
#pragma unroll
      for (int fm = 0; fm < 4; fm++)
#pragma unroll
        for (int fn = 0; fn < 4; fn++)
          acc[fm][fn] = __builtin_amdgcn_mfma_f32_16x16x32_bf16(af[fm], bfg[fn], acc[fm][fn], 0, 0, 0);
    }
  }

#pragma unroll
  for (int fm = 0; fm < 4; fm++) {
#pragma unroll
    for (int fn = 0; fn < 4; fn++) {
      int col = n0 + wn + fn * 16 + fr;          // 0..383 within head
      float badd = 0.f; bool act = false;
      if (col >= 256) { badd = bv[e * 128 + (col - 256)]; act = true; }
      us16* op = ksv4 + (long)(m0 + wm + fm * 16 + rbase) * 12288 + e * 3072 + z * 384 + col;
#pragma unroll
      for (int j = 0; j < 4; j++) {
        float v = acc[fm][fn][j] + badd;
        if (act) v = lrelu(v);
        op[(long)j * 12288] = f2bf(v);
      }
    }
  }
}

// ---------------------------------------------------------------------------
// Fused 2-MLP DOT GEMM (r14 proven; fallback if dyn-LDS denied). 8-slot PART.
// ---------------------------------------------------------------------------
__global__ __launch_bounds__(256, 4)
void dot2_k(const us16* __restrict__ encC, const us16* __restrict__ encV,
            const us16* __restrict__ other,
            const us16* __restrict__ wc1t, const us16* __restrict__ wv1t,
            const float* __restrict__ bc1, const float* __restrict__ bv1,
            const float* __restrict__ wc2, const float* __restrict__ wv2,
            float* __restrict__ partial)
{
  __shared__ us16 lA[128 * 64];
  __shared__ us16 lB[128 * 64];
  constexpr int KTOT = 1024;
  const int tid = threadIdx.x;
  const int zz = blockIdx.z;
  const int half = zz >> 3, z = zz & 7;
  const us16* Ap  = half ? encV : encC;
  const us16* Btp = half ? wv1t : wc1t;
  const float* bias = half ? bv1 : bc1;
  const float* dotW = half ? wv2 : wc2;
  const int m0 = blockIdx.x * 128;
  const int n0 = blockIdx.y * 128;
  const int wv = tid >> 6, lane = tid & 63;
  const int wm = (wv >> 1) * 64, wn = (wv & 1) * 64;
  const int fr = lane & 15, fk = (lane >> 4) * 8;
  const int rbase = (lane >> 4) * 4;
  const int xorkey = (fr & 7) << 3;

  f32x4 acc[4][4];
#pragma unroll
  for (int i = 0; i < 4; i++)
#pragma unroll
    for (int j = 0; j < 4; j++) acc[i][j] = f32x4{0.f, 0.f, 0.f, 0.f};

  const us16* bbase = Btp + (long)z * 512 * 1024 + (long)n0 * KTOT;
  const long aSlice = (long)8192 * 512;

  for (int k0 = 0; k0 < KTOT; k0 += 64) {
    __syncthreads();
#pragma unroll
    for (int i = 0; i < 4; i++) {
      const int c = i * 256 + tid;
      const int r = c >> 3;
      const int col = ((c & 7) ^ (r & 7)) << 3;
      const int kg = k0 + col;
      const us16* a = (kg < 512) ? Ap    + (long)z * aSlice + (long)(m0 + r) * 512 + kg
                                 : other + (long)z * aSlice + (long)(m0 + r) * 512 + (kg - 512);
      gload16(a, &lA[c * 8]);
    }
#pragma unroll
    for (int i = 0; i < 4; i++) {
      const int c = i * 256 + tid;
      const int r = c >> 3;
      const int col = ((c & 7) ^ (r & 7)) << 3;
      gload16(bbase + (long)r * KTOT + (k0 + col), &lB[c * 8]);
    }
    __syncthreads();

#pragma unroll
    for (int ks = 0; ks < 2; ks++) {
      bf16x8 af[4], bfg[4];
      const int kc = ks * 32 + fk;
#pragma unroll
      for (int f = 0; f < 4; f++)
        af[f]  = *(const bf16x8*)&lA[(wm + f * 16 + fr) * 64 + (kc ^ xorkey)];
#pragma unroll
      for (int f = 0; f < 4; f++)
        bfg[f] = *(const bf16x8*)&lB[(wn + f * 16 + fr) * 64 + (kc ^ xorkey)];
#pragma unroll
      for (int fm = 0; fm < 4; fm++)
#pragma unroll
        for (int fn = 0; fn < 4; fn++)
          acc[fm][fn] = __builtin_amdgcn_mfma_f32_16x16x32_bf16(af[fm], bfg[fn], acc[fm][fn], 0, 0, 0);
    }
  }

  const float* bsl = bias + (long)z * 512;
  const float* wsl = dotW + (long)z * 512;
#pragma unroll
  for (int fm = 0; fm < 4; fm++) {
#pragma unroll
    for (int j = 0; j < 4; j++) {
      float p = 0.f;
#pragma unroll
      for (int fn = 0; fn < 4; fn++) {
        int col = n0 + wn + fn * 16 + fr;
        float v = acc[fm][fn][j] + bsl[col];
        v = lrelu(v);
        p += v * wsl[col];
      }
      p += __shfl_xor(p, 1); p += __shfl_xor(p, 2); p += __shfl_xor(p, 4); p += __shfl_xor(p, 8);
      if (fr == 0) {
        long row = (long)half * 65536 + (long)z * 8192 + (m0 + wm + fm * 16 + rbase + j);
        partial[row * 8 + blockIdx.y * 2 + (wv & 1)] = p;
      }
    }
  }
}

// ---------------------------------------------------------------------------
// COUNTED-VMCNT DOT GEMM (T4): BM=256, BN=128, BK=64; 3 LDS buffers (144 KB).
// 512 thr = 8 waves (2M x 4N); per-wave out 128x32; 6 gloads/thread/K-tile.
// Per tile t: vmcnt(6) [tile t's loads, issued 2 tiles ago, land; t+1's 6 stay
// in flight] -> barrier -> stage(t+2) -> ds_read + 32 MFMA/wave -> barrier.
// grid (32, 4, 16): zz<8 critic, else value. PART has 16 slots/row.
// ---------------------------------------------------------------------------
__global__ __launch_bounds__(512, 1)
void dotP_k(const us16* __restrict__ encC, const us16* __restrict__ encV,
            const us16* __restrict__ other,
            const us16* __restrict__ wc1t, const us16* __restrict__ wv1t,
            const float* __restrict__ bc1, const float* __restrict__ bv1,
            const float* __restrict__ wc2, const float* __restrict__ wv2,
            float* __restrict__ partial)
{
  extern __shared__ us16 lds[];   // 3 * 24576 elems = 147456 B
  constexpr int KTOT = 1024;
  const int tid = threadIdx.x;
  const int zz = blockIdx.z;
  const int half = zz >> 3, z = zz & 7;
  const us16* Ap  = half ? encV : encC;
  const us16* Btp = half ? wv1t : wc1t;
  const float* bias = half ? bv1 : bc1;
  const float* dotW = half ? wv2 : wc2;
  const int m0 = blockIdx.x * 256;
  const int n0 = blockIdx.y * 128;
  const int wv = tid >> 6, lane = tid & 63;
  const int wr = wv >> 2, wc = wv & 3;           // 2 x 4 waves
  const int wmBase = wr * 128, wnBase = wc * 32;
  const int fr = lane & 15, fk = (lane >> 4) * 8;
  const int rbase = (lane >> 4) * 4;
  const int srow = tid >> 3;                     // 0..63
  const int scol = ((tid & 7) ^ (srow & 7)) << 3;
  const long aSlice = (long)8192 * 512;
  const us16* bb = Btp + (long)z * 512 * 1024 + (long)n0 * KTOT;

  f32x4 acc[8][2];
#pragma unroll
  for (int i = 0; i < 8; i++)
#pragma unroll
    for (int j = 0; j < 2; j++) acc[i][j] = f32x4{0.f, 0.f, 0.f, 0.f};

  auto stage = [&](int t, int buf) {   // 6 gloads: A (4 x 64 rows), B (2 x 64 rows)
    us16* base = lds + buf * 24576;
    const int k0 = t * 64;
    const int kg = k0 + scol;
#pragma unroll
    for (int g = 0; g < 4; g++) {
      const int r = g * 64 + srow;
      const us16* a = (kg < 512) ? Ap    + (long)z * aSlice + (long)(m0 + r) * 512 + kg
                                 : other + (long)z * aSlice + (long)(m0 + r) * 512 + (kg - 512);
      gload16(a, base + g * 4096 + tid * 8);
    }
#pragma unroll
    for (int g = 0; g < 2; g++) {
      const int r = g * 64 + srow;
      gload16(bb + (long)r * KTOT + (k0 + scol), base + 16384 + g * 4096 + tid * 8);
    }
  };

  constexpr int NT = KTOT / 64;  // 16
  stage(0, 0);
  stage(1, 1);

  int cur = 0;
#pragma unroll 1
  for (int t = 0; t < NT; ++t) {
    if (t + 1 < NT) asm volatile("s_waitcnt vmcnt(6)" ::: "memory");  // tile t resident; t+1 in flight
    else            asm volatile("s_waitcnt vmcnt(0)" ::: "memory");
    __builtin_amdgcn_sched_barrier(0);
    __builtin_amdgcn_s_barrier();
    __builtin_amdgcn_sched_barrier(0);

    // buffer (cur+2)%3 was read in iter t-1 (fenced by its end barrier)
    const int nxt2 = (cur >= 1) ? cur - 1 : cur + 2;
    if (t + 2 < NT) stage(t + 2, nxt2);

    const us16* curA = lds + cur * 24576;
    const us16* curB = curA + 16384;

    bf16x8 bfg[2][2];
#pragma unroll
    for (int fn = 0; fn < 2; fn++)
#pragma unroll
      for (int ks = 0; ks < 2; ks++) {
        const int row = wnBase + fn * 16 + fr;
        bfg[fn][ks] = *(const bf16x8*)&curB[row * 64 + ((ks * 32 + fk) ^ ((row & 7) << 3))];
      }
    __builtin_amdgcn_s_setprio(1);
#pragma unroll
    for (int fm = 0; fm < 8; fm++) {
      bf16x8 af0, af1;
      const int row = wmBase + fm * 16 + fr;
      af0 = *(const bf16x8*)&curA[row * 64 + ((fk) ^ ((row & 7) << 3))];
      af1 = *(const bf16x8*)&curA[row * 64 + ((32 + fk) ^ ((row & 7) << 3))];
#pragma unroll
      for (int fn = 0; fn < 2; fn++) {
        acc[fm][fn] = __builtin_amdgcn_mfma_f32_16x16x32_bf16(af0, bfg[fn][0], acc[fm][fn], 0, 0, 0);
        acc[fm][fn] = __builtin_amdgcn_mfma_f32_16x16x32_bf16(af1, bfg[fn][1], acc[fm][fn], 0, 0, 0);
      }
    }
    __builtin_amdgcn_s_setprio(0);
    __builtin_amdgcn_s_barrier();              // readers of buf cur done
    __builtin_amdgcn_sched_barrier(0);
    cur = (cur + 1 < 3) ? cur + 1 : 0;
  }

  // epilogue: hidden = lrelu(acc + b1[col]); partial += hidden * W2[col]
  const float* bsl = bias + (long)z * 512;
  const float* wsl = dotW + (long)z * 512;
#pragma unroll
  for (int fm = 0; fm < 8; fm++) {
#pragma unroll
    for (int j = 0; j < 4; j++) {
      float p = 0.f;
#pragma unroll
      for (int fn = 0; fn < 2; fn++) {
        int col = n0 + wnBase + fn * 16 + fr;
        float v = acc[fm][fn][j] + bsl[col];
        v = lrelu(v);
        p += v * wsl[col];
      }
      p += __shfl_xor(p, 1); p += __shfl_xor(p, 2); p += __shfl_xor(p, 4); p += __shfl_xor(p, 8);
      if (fr == 0) {
        long row = (long)half * 65536 + (long)z * 8192 + (m0 + wmBase + fm * 16 + rbase + j);
        partial[row * 16 + blockIdx.y * 4 + wc] = p;
      }
    }
  }
}

// ---------------------------------------------------------------------------
// Attention core + wrappers (Tier B / A2 / A4). launch_bounds (256,4).
// ---------------------------------------------------------------------------
DEVI void attn_core(const us16* __restrict__ src, us16* __restrict__ other,
                    int e, long b, int lane, us16* tbuf)
{
#pragma unroll
  for (int i = 0; i < 6; i++) {
    int c = i * 64 + lane;
    int r = c / 48, cc = c - r * 48;
    *(int4*)&tbuf[r * 392 + cc * 8] = *(const int4*)&src[c * 8];
  }
  __syncthreads();
  const int i = lane >> 3, j = lane & 7;
  const us16* selp = &tbuf[i * 392 + 128];
  const us16* keyp = &tbuf[j * 392];
  float acc = 0.f;
#pragma unroll
  for (int d = 0; d < 128; d += 8) {
    u16x8 s8 = *(const u16x8*)&selp[d];
    u16x8 k8 = *(const u16x8*)&keyp[d];
#pragma unroll
    for (int q = 0; q < 8; q++) acc += bf2f(s8[q]) * bf2f(k8[q]);
  }
  acc *= 0.088388347648318447f;
  float mx = acc;
  mx = fmaxf(mx, __shfl_xor(mx, 1)); mx = fmaxf(mx, __shfl_xor(mx, 2)); mx = fmaxf(mx, __shfl_xor(mx, 4));
  float ex = __expf(acc - mx);
  float sm = ex;
  sm += __shfl_xor(sm, 1); sm += __shfl_xor(sm, 2); sm += __shfl_xor(sm, 4);
  float wsm = ex / sm;
  float wj[8];
  const int ibase = lane & 56;
#pragma unroll
  for (int jj = 0; jj < 8; jj++) wj[jj] = __shfl(wsm, ibase + jj);
  const int dbase = (lane & 7) * 16;
  float o[16];
#pragma unroll
  for (int q = 0; q < 16; q++) o[q] = 0.f;
#pragma unroll
  for (int jj = 0; jj < 8; jj++) {
    u16x8 v0 = *(const u16x8*)&tbuf[jj * 392 + 256 + dbase];
    u16x8 v1 = *(const u16x8*)&tbuf[jj * 392 + 256 + dbase + 8];
    float wgt = wj[jj];
#pragma unroll
    for (int q = 0; q < 8; q++) { o[q] += wgt * bf2f(v0[q]); o[8 + q] += wgt * bf2f(v1[q]); }
  }
  u16x8 r0, r1;
#pragma unroll
  for (int q = 0; q < 8; q++) { r0[q] = f2bf(o[q]); r1[q] = f2bf(o[8 + q]); }
  us16* dst = other + ((long)i * 8192 + b) * 512 + e * 128 + dbase;
  *(u16x8*)&dst[0] = r0;
  *(u16x8*)&dst[8] = r1;
}

__global__ __launch_bounds__(256, 4)
void attn_k(const us16* __restrict__ ksv, us16* __restrict__ other, int e)
{
  __shared__ us16 t[4][8 * 392];
  const int wv = threadIdx.x >> 6, lane = threadIdx.x & 63;
  const long b = (long)blockIdx.x * 4 + wv;
  attn_core(ksv + b * 3072, other, e, b, lane, &t[wv][0]);
}

__global__ __launch_bounds__(256, 4)
void attn2_k(const us16* __restrict__ ksv2, us16* __restrict__ other, int ebase)
{
  __shared__ us16 t[4][8 * 392];
  const int wv = threadIdx.x >> 6, lane = threadIdx.x & 63;
  const long b = (long)blockIdx.x * 4 + wv;
  const int el = blockIdx.y;
  attn_core(ksv2 + b * 6144 + el * 3072, other, ebase + el, b, lane, &t[wv][0]);
}

__global__ __launch_bounds__(256, 4)
void attn4_k(const us16* __restrict__ ksv4, us16* __restrict__ other)
{
  __shared__ us16 t[4][8 * 392];
  const int wv = threadIdx.x >> 6, lane = threadIdx.x & 63;
  const long b = (long)blockIdx.x * 4 + wv;
  const int e = blockIdx.y;
  attn_core(ksv4 + b * 12288 + e * 3072, other, e, b, lane, &t[wv][0]);
}

// 8-slot reduce (dot2 path): r < 65536 -> q (bc2), else v (bv2).
__global__ void reduce2_k(const float* __restrict__ part, const float* __restrict__ b2c,
                          const float* __restrict__ b2v, float* __restrict__ out)
{
  int r = blockIdx.x * 256 + threadIdx.x;   // 0..131071
  const float4* p = (const float4*)(part + (long)r * 8);
  float4 a = p[0], b = p[1];
  float s = ((a.x + a.y) + (a.z + a.w)) + ((b.x + b.y) + (b.z + b.w));
  int agent = (r >> 13) & 7;
  out[r] = s + ((r < 65536) ? b2c[agent] : b2v[agent]);
}

// 16-slot reduce (dotP path).
__global__ void reduce16_k(const float* __restrict__ part, const float* __restrict__ b2c,
                           const float* __restrict__ b2v, float* __restrict__ out)
{
  int r = blockIdx.x * 256 + threadIdx.x;   // 0..131071
  const float4* p = (const float4*)(part + (long)r * 16);
  float s = 0.f;
#pragma unroll
  for (int i = 0; i < 4; i++) {
    float4 a = p[i];
    s += ((a.x + a.y) + (a.z + a.w));
  }
  int agent = (r >> 13) & 7;
  out[r] = s + ((r < 65536) ? b2c[agent] : b2v[agent]);
}

// ---------------------------------------------------------------------------
extern "C" void kernel_launch(void* const* d_in, const int* in_sizes, int n_in,
                              void* d_out, int out_size, void* d_ws, size_t ws_size,
                              hipStream_t stream)
{
  const float* states = (const float*)d_in[0];
  const float* actions= (const float*)d_in[1];
  const float* Ws  = (const float*)d_in[2];
  const float* bs  = (const float*)d_in[3];
  const float* Wsa = (const float*)d_in[4];
  const float* bsa = (const float*)d_in[5];
  const float* Wk  = (const float*)d_in[6];
  const float* Wsel= (const float*)d_in[7];
  const float* Wv  = (const float*)d_in[8];
  const float* bv  = (const float*)d_in[9];
  const float* Wc1 = (const float*)d_in[10];
  const float* bc1 = (const float*)d_in[11];
  const float* Wc2 = (const float*)d_in[12];
  const float* bc2 = (const float*)d_in[13];
  const float* Wv1 = (const float*)d_in[14];
  const float* bv1 = (const float*)d_in[15];
  const float* Wv2 = (const float*)d_in[16];
  const float* bv2 = (const float*)d_in[17];

  char* ws = (char*)d_ws;
  constexpr size_t OFF_WST   = 0;
  constexpr size_t OFF_WSAT  = OFF_WST   + (size_t)8 * 512 * 64 * 2;
  constexpr size_t OFF_WKVST = OFF_WSAT  + (size_t)8 * 512 * 96 * 2;
  constexpr size_t OFF_WC1T  = OFF_WKVST + (size_t)4 * 384 * 512 * 2;
  constexpr size_t OFF_WV1T  = OFF_WC1T  + (size_t)8 * 512 * 1024 * 2;
  constexpr size_t OFF_ENC   = OFF_WV1T  + (size_t)8 * 512 * 1024 * 2;
  constexpr size_t OFF_OTHER = OFF_ENC   + (size_t)8 * 8192 * 512 * 2;
  constexpr size_t OFF_KSV   = OFF_OTHER + (size_t)8 * 8192 * 512 * 2;
  // Tier B: KSV (one head) + PART (8-slot)
  constexpr size_t OFF_PARTB = OFF_KSV   + (size_t)8192 * 8 * 384 * 2;
  constexpr size_t NEED_B    = OFF_PARTB + (size_t)131072 * 8 * 4;
  // Tier A2: KSV2 (two heads); PART(8) + ENC2 aliased inside.
  constexpr size_t KSV2_BYTES = (size_t)8192 * 2 * 8 * 384 * 2;
  constexpr size_t NEED_A2    = OFF_KSV + KSV2_BYTES;               // ~254.5 MB
  // Tier A4: KSV4 (four heads); PART(16) + ENC2 aliased inside.
  constexpr size_t KSV4_BYTES = (size_t)8192 * 4 * 8 * 384 * 2;
  constexpr size_t NEED_A4    = OFF_KSV + KSV4_BYTES;               // ~355 MB
  constexpr size_t OFF_PARTA  = OFF_KSV;                            // 4.2 / 8.4 MB
  constexpr size_t OFF_ENC2_8 = OFF_KSV + (size_t)131072 * 8 * 4;   // dot2 layout
  constexpr size_t OFF_ENC2_16= OFF_KSV + (size_t)131072 * 16 * 4;  // dotP layout
  if (ws_size < NEED_B) return;
  const int tier = (ws_size >= NEED_A4) ? 2 : (ws_size >= NEED_A2) ? 1 : 0;

  us16* WST   = (us16*)(ws + OFF_WST);
  us16* WSAT  = (us16*)(ws + OFF_WSAT);
  us16* WKVST = (us16*)(ws + OFF_WKVST);
  us16* WC1T  = (us16*)(ws + OFF_WC1T);
  us16* WV1T  = (us16*)(ws + OFF_WV1T);
  us16* ENC   = (us16*)(ws + OFF_ENC);
  us16* OTHER = (us16*)(ws + OFF_OTHER);
  us16* KSV   = (us16*)(ws + OFF_KSV);
  float* PARTB= (float*)(ws + OFF_PARTB);
  float* PARTA= (float*)(ws + OFF_PARTA);

  // 144 KiB dynamic LDS opt-in for the counted-vmcnt DOT kernel.
  const bool pipeOK =
      hipFuncSetAttribute((const void*)dotP_k,
                          hipFuncAttributeMaxDynamicSharedMemorySize, 147456) == hipSuccess;
  us16* ENC2 = (us16*)(ws + (pipeOK ? OFF_ENC2_16 : OFF_ENC2_8));

  dim3 tb(32, 8);
  tconvSA_k<<<dim3(3, 16, 16), tb, 0, stream>>>(Ws, Wsa, WST, WSAT);
  tconv3_k <<<dim3(16, 4, 12), tb, 0, stream>>>(Wk, Wsel, Wv, WKVST);
  tconvC_k <<<dim3(32, 16, 16),tb, 0, stream>>>(Wc1, Wv1, WC1T, WV1T);

  // sa_enc = lrelu([states|actions] @ Wsa + bsa)  -> ENC (bf16)
  enc_gemm_k<ASRC_F32_CAT, 96><<<dim3(64, 4, 8), 256, 0, stream>>>(
      states, (long)8192 * 64, actions, (long)8192 * 16, WSAT, (long)512 * 96, bsa, 512,
      ENC, (long)8192 * 512, 512);

  if (tier == 2) {
    // all 4 heads: one KSV GEMM + one attention
    ksv4_k<<<dim3(64, 12, 8), 256, 0, stream>>>(ENC, WKVST, bv, KSV);
    attn4_k<<<dim3(2048, 4), 256, 0, stream>>>(KSV, OTHER);
    // s_enc -> ENC2 (aliased in the now-dead KSV4 region; stream-serial)
    enc_gemm_k<ASRC_F32, 64><<<dim3(64, 4, 8), 256, 0, stream>>>(
        states, (long)8192 * 64, nullptr, 0, WST, (long)512 * 64, bs, 512,
        ENC2, (long)8192 * 512, 512);
    if (pipeOK) {
      dotP_k<<<dim3(32, 4, 16), 512, 147456, stream>>>(
          ENC, ENC2, OTHER, WC1T, WV1T, bc1, bv1, Wc2, Wv2, PARTA);
      reduce16_k<<<dim3(512), 256, 0, stream>>>(PARTA, bc2, bv2, (float*)d_out);
    } else {
      dot2_k<<<dim3(64, 4, 16), 256, 0, stream>>>(
          ENC, ENC2, OTHER, WC1T, WV1T, bc1, bv1, Wc2, Wv2, PARTA);
      reduce2_k<<<dim3(512), 256, 0, stream>>>(PARTA, bc2, bv2, (float*)d_out);
    }
  } else if (tier == 1) {
    for (int h = 0; h < 2; h++) {
      ksv2_k<<<dim3(64, 6, 8), 256, 0, stream>>>(
          ENC, WKVST + (size_t)(h * 2) * 384 * 512, bv + h * 256, KSV);
      attn2_k<<<dim3(2048, 2), 256, 0, stream>>>(KSV, OTHER, h * 2);
    }
    us16* ENC2b = (us16*)(ws + OFF_ENC2_8);
    enc_gemm_k<ASRC_F32, 64><<<dim3(64, 4, 8), 256, 0, stream>>>(
        states, (long)8192 * 64, nullptr, 0, WST, (long)512 * 64, bs, 512,
        ENC2b, (long)8192 * 512, 512);
    dot2_k<<<dim3(64, 4, 16), 256, 0, stream>>>(
        ENC, ENC2b, OTHER, WC1T, WV1T, bc1, bv1, Wc2, Wv2, PARTA);
    reduce2_k<<<dim3(512), 256, 0, stream>>>(PARTA, bc2, bv2, (float*)d_out);
  } else {
    for (int e = 0; e < 4; e++) {
      gemm64_k<false, EPI_KSV, 512><<<dim3(64, 3, 8), 256, 0, stream>>>(
          ENC, (long)8192 * 512, nullptr, 0, WKVST + (size_t)e * 384 * 512, 0, bv + e * 128,
          KSV, 384, 3072, nullptr, nullptr);
      attn_k<<<dim3(2048), 256, 0, stream>>>(KSV, OTHER, e);
    }
    gemm64_k<true, EPI_DOT, 1024><<<dim3(64, 4, 8), 256, 0, stream>>>(
        ENC, (long)8192 * 512, OTHER, (long)8192 * 512, WC1T, (long)512 * 1024, bc1,
        nullptr, 0, 0, Wc2, PARTB);
    enc_gemm_k<ASRC_F32, 64><<<dim3(64, 4, 8), 256, 0, stream>>>(
        states, (long)8192 * 64, nullptr, 0, WST, (long)512 * 64, bs, 512,
        ENC, (long)8192 * 512, 512);
    gemm64_k<true, EPI_DOT, 1024><<<dim3(64, 4, 8), 256, 0, stream>>>(
        ENC, (long)8192 * 512, OTHER, (long)8192 * 512, WV1T, (long)512 * 1024, bv1,
        nullptr, 0, 0, Wv2, PARTB + (size_t)65536 * 8);
    reduce2_k<<<dim3(512), 256, 0, stream>>>(PARTB, bc2, bv2, (float*)d_out);
  }
}

// Round 16
// 391.021 us; speedup vs baseline: 1.0065x; 1.0065x over previous
//
#include <hip/hip_runtime.h>

// ---------------------------------------------------------------------------
// AttentionCritic on MI355X — round 16: counted-vmcnt DOT GEMM sized to the
// grantable 128 KiB: A 3-buffered (3x32KB) + B 2-buffered (2x16KB).
// Per tile: vmcnt(4) (A issued 2 iters ago, B 1 iter ago land; A(t+1) stays
// in flight) -> barrier -> stage B(t+1),A(t+2) -> ds_read+MFMA -> barrier.
// Fallback to proven dot2_k if opt-in denied. Everything else = r14 (393 us).
// ---------------------------------------------------------------------------

#define DEVI __device__ __forceinline__

typedef unsigned short us16;
typedef __bf16 bf16x8 __attribute__((ext_vector_type(8)));
typedef float f32x4 __attribute__((ext_vector_type(4)));
typedef unsigned short u16x8 __attribute__((ext_vector_type(8)));

DEVI us16 f2bf(float f) {
  unsigned u = __builtin_bit_cast(unsigned, f);
  u += 0x7FFFu + ((u >> 16) & 1u);          // round-to-nearest-even
  return (us16)(u >> 16);
}
DEVI float bf2f(us16 h) {
  unsigned u = ((unsigned)h) << 16;
  return __builtin_bit_cast(float, u);
}
DEVI float lrelu(float v) { return v > 0.f ? v : 0.01f * v; }
DEVI int pk2(float a, float b) { return (int)f2bf(a) | ((int)f2bf(b) << 16); }

// async global->LDS, 16B per lane. LDS dest must be linear: base + lane*16.
DEVI void gload16(const us16* g, us16* l) {
  __builtin_amdgcn_global_load_lds(
      (const __attribute__((address_space(1))) void*)g,
      (__attribute__((address_space(3))) void*)l, 16, 0, 0);
}

// ---------------------------------------------------------------------------
// Transposes (fp32 -> bf16, [K][O] -> [O][Kpad])
// ---------------------------------------------------------------------------
__global__ void tconvSA_k(const float* __restrict__ wsrc, const float* __restrict__ wsasrc,
                          us16* __restrict__ wst, us16* __restrict__ wsat)
{
  __shared__ float t[32][33];
  const int zz = blockIdx.z;               // 0..15
  const int m = zz >> 3, s = zz & 7;
  const int K = m ? 80 : 64, Kpad = m ? 96 : 64;
  const float* src = m ? (wsasrc + (long)s * 80 * 512) : (wsrc + (long)s * 64 * 512);
  us16* dst = m ? (wsat + (long)s * 512 * 96) : (wst + (long)s * 512 * 64);
  const int k0 = blockIdx.x * 32, o0 = blockIdx.y * 32;
  const int lx = threadIdx.x, ly = threadIdx.y;
#pragma unroll
  for (int i = 0; i < 4; i++) {
    int k = k0 + ly + i * 8, o = o0 + lx;
    float v = 0.f;
    if (k < K) v = src[(long)k * 512 + o];
    t[ly + i * 8][lx] = v;
  }
  __syncthreads();
#pragma unroll
  for (int i = 0; i < 4; i++) {
    int o = o0 + ly + i * 8, k = k0 + lx;
    if (k < Kpad)
      dst[(long)o * Kpad + k] = f2bf(t[lx][ly + i * 8]);
  }
}

__global__ void tconv3_k(const float* __restrict__ wk, const float* __restrict__ wsel,
                         const float* __restrict__ wv, us16* __restrict__ dst)
{
  __shared__ float t[32][33];
  const int zz = blockIdx.z;               // 0..11
  const int e = zz & 3, m = zz >> 2;       // m: 0=key 1=sel 2=val
  const float* src = ((m == 0) ? wk : (m == 1) ? wsel : wv) + (long)e * 512 * 128;
  us16* d = dst + (long)e * 384 * 512 + (long)(m * 128) * 512;
  const int k0 = blockIdx.x * 32, o0 = blockIdx.y * 32;
  const int lx = threadIdx.x, ly = threadIdx.y;
#pragma unroll
  for (int i = 0; i < 4; i++)
    t[ly + i * 8][lx] = src[(long)(k0 + ly + i * 8) * 128 + (o0 + lx)];
  __syncthreads();
#pragma unroll
  for (int i = 0; i < 4; i++)
    d[(long)(o0 + ly + i * 8) * 512 + (k0 + lx)] = f2bf(t[lx][ly + i * 8]);
}

__global__ void tconvC_k(const float* __restrict__ c1, const float* __restrict__ v1,
                         us16* __restrict__ dc, us16* __restrict__ dv)
{
  __shared__ float t[32][33];
  const int zz = blockIdx.z;               // 0..15
  const int n = zz & 7, m = zz >> 3;
  const float* src = ((m == 0) ? c1 : v1) + (long)n * 1024 * 512;
  us16* dst = ((m == 0) ? dc : dv) + (long)n * 512 * 1024;
  const int k0 = blockIdx.x * 32, o0 = blockIdx.y * 32;
  const int lx = threadIdx.x, ly = threadIdx.y;
#pragma unroll
  for (int i = 0; i < 4; i++)
    t[ly + i * 8][lx] = src[(long)(k0 + ly + i * 8) * 512 + (o0 + lx)];
  __syncthreads();
#pragma unroll
  for (int i = 0; i < 4; i++)
    dst[(long)(o0 + ly + i * 8) * 1024 + (k0 + lx)] = f2bf(t[lx][ly + i * 8]);
}

// ---------------------------------------------------------------------------
// fp32-input encoder GEMM (proven, BK=32, linear LDS).
// ---------------------------------------------------------------------------
enum { ASRC_F32 = 2, ASRC_F32_CAT = 3 };

template <int ASRC, int KTOT>
__global__ __launch_bounds__(256, 4)
void enc_gemm_k(const float* __restrict__ Ap, long aSlice,
                const float* __restrict__ A2p, long a2Slice,
                const us16* __restrict__ Btp, long bSlice,
                const float* __restrict__ bias, long biasSlice,
                us16* __restrict__ outB, long outSlice, long outRow)
{
  __shared__ us16 lA[128 * 32];
  __shared__ us16 lB[128 * 32];
  const int tid = threadIdx.x;
  const int z = blockIdx.z;
  const int m0 = blockIdx.x * 128;
  const int n0 = blockIdx.y * 128;
  const int wv = tid >> 6, lane = tid & 63;
  const int wm = (wv >> 1) * 64, wn = (wv & 1) * 64;
  const int fr = lane & 15, fk = (lane >> 4) * 8;
  const int rbase = (lane >> 4) * 4;
  const int grow = tid >> 2, gcol = (tid & 3) * 8;

  f32x4 acc[4][4];
#pragma unroll
  for (int i = 0; i < 4; i++)
#pragma unroll
    for (int j = 0; j < 4; j++) acc[i][j] = f32x4{0.f, 0.f, 0.f, 0.f};

  const us16* bbase = Btp + (long)z * bSlice + (long)n0 * KTOT;

  for (int k0 = 0; k0 < KTOT; k0 += 32) {
    int4 ra0, ra1;
    {
      const int srow = tid >> 1, scol0 = (tid & 1) * 16;
      const int kg = k0 + scol0;
      const float* a = nullptr;
      if constexpr (ASRC == ASRC_F32) {
        a = Ap + (long)z * aSlice + (long)(m0 + srow) * 64 + kg;
      } else {  // states(0..63) | actions(64..79) | zero pad(80..95)
        if (kg < 64)      a = Ap + (long)z * aSlice + (long)(m0 + srow) * 64 + kg;
        else if (kg < 80) a = A2p + (long)z * a2Slice + (long)(m0 + srow) * 16 + (kg - 64);
      }
      float4 f0, f1, f2, f3;
      if (a) { const float4* ap = (const float4*)a; f0 = ap[0]; f1 = ap[1]; f2 = ap[2]; f3 = ap[3]; }
      else   { f0 = make_float4(0.f, 0.f, 0.f, 0.f); f1 = f0; f2 = f0; f3 = f0; }
      ra0.x = pk2(f0.x, f0.y); ra0.y = pk2(f0.z, f0.w); ra0.z = pk2(f1.x, f1.y); ra0.w = pk2(f1.z, f1.w);
      ra1.x = pk2(f2.x, f2.y); ra1.y = pk2(f2.z, f2.w); ra1.z = pk2(f3.x, f3.y); ra1.w = pk2(f3.z, f3.w);
    }

    __syncthreads();
    {
      const us16* bb = bbase + k0 + gcol;
      gload16(bb + (long)grow * KTOT, &lB[tid * 8]);
      gload16(bb + (long)(64 + grow) * KTOT, &lB[2048 + tid * 8]);
    }
    {
      const int srow = tid >> 1, scol0 = (tid & 1) * 16;
      *(int4*)&lA[srow * 32 + scol0]     = ra0;
      *(int4*)&lA[srow * 32 + scol0 + 8] = ra1;
    }
    __syncthreads();

    bf16x8 af[4], bfg[4];
#pragma unroll
    for (int f = 0; f < 4; f++) af[f]  = *(const bf16x8*)&lA[(wm + f * 16 + fr) * 32 + fk];
#pragma unroll
    for (int f = 0; f < 4; f++) bfg[f] = *(const bf16x8*)&lB[(wn + f * 16 + fr) * 32 + fk];
#pragma unroll
    for (int fm = 0; fm < 4; fm++)
#pragma unroll
      for (int fn = 0; fn < 4; fn++)
        acc[fm][fn] = __builtin_amdgcn_mfma_f32_16x16x32_bf16(af[fm], bfg[fn], acc[fm][fn], 0, 0, 0);
  }

#pragma unroll
  for (int fm = 0; fm < 4; fm++) {
#pragma unroll
    for (int fn = 0; fn < 4; fn++) {
      int col = n0 + wn + fn * 16 + fr;
      float badd = bias[(long)z * biasSlice + col];
      us16* op = outB + (long)z * outSlice + (long)(m0 + wm + fm * 16 + rbase) * outRow + col;
#pragma unroll
      for (int j = 0; j < 4; j++) {
        float v = lrelu(acc[fm][fn][j] + badd);
        op[(long)j * outRow] = f2bf(v);
      }
    }
  }
}

// ---------------------------------------------------------------------------
// Proven 128^2 bf16 GEMM (BK=64, XOR-swizzle, 2-barrier) — Tier B forms.
// ---------------------------------------------------------------------------
enum { EPI_KSV = 1, EPI_DOT = 2 };

template <bool CAT, int EPI, int KTOT>
__global__ __launch_bounds__(256, 4)
void gemm64_k(const us16* __restrict__ Ap, long aSlice,
              const us16* __restrict__ A2p, long a2Slice,
              const us16* __restrict__ Btp, long bSlice,
              const float* __restrict__ bias,
              us16* __restrict__ outB, long outSlice, long outRow,
              const float* __restrict__ dotW, float* __restrict__ partial)
{
  __shared__ us16 lA[128 * 64];
  __shared__ us16 lB[128 * 64];
  const int tid = threadIdx.x;
  const int z = blockIdx.z;
  const int m0 = blockIdx.x * 128;
  const int n0 = blockIdx.y * 128;
  const int wv = tid >> 6, lane = tid & 63;
  const int wm = (wv >> 1) * 64, wn = (wv & 1) * 64;
  const int fr = lane & 15, fk = (lane >> 4) * 8;
  const int rbase = (lane >> 4) * 4;
  const int xorkey = (fr & 7) << 3;

  f32x4 acc[4][4];
#pragma unroll
  for (int i = 0; i < 4; i++)
#pragma unroll
    for (int j = 0; j < 4; j++) acc[i][j] = f32x4{0.f, 0.f, 0.f, 0.f};

  const us16* bbase = Btp + (long)z * bSlice + (long)n0 * KTOT;

  for (int k0 = 0; k0 < KTOT; k0 += 64) {
    __syncthreads();
#pragma unroll
    for (int i = 0; i < 4; i++) {
      const int c = i * 256 + tid;
      const int r = c >> 3;
      const int col = ((c & 7) ^ (r & 7)) << 3;
      const us16* a;
      if constexpr (!CAT) {
        a = Ap + (long)z * aSlice + (long)(m0 + r) * KTOT + (k0 + col);
      } else {
        const int kg = k0 + col;
        a = (kg < 512) ? Ap  + (long)z * aSlice  + (long)(m0 + r) * 512 + kg
                       : A2p + (long)z * a2Slice + (long)(m0 + r) * 512 + (kg - 512);
      }
      gload16(a, &lA[c * 8]);
    }
#pragma unroll
    for (int i = 0; i < 4; i++) {
      const int c = i * 256 + tid;
      const int r = c >> 3;
      const int col = ((c & 7) ^ (r & 7)) << 3;
      gload16(bbase + (long)r * KTOT + (k0 + col), &lB[c * 8]);
    }
    __syncthreads();

#pragma unroll
    for (int ks = 0; ks < 2; ks++) {
      bf16x8 af[4], bfg[4];
      const int kc = ks * 32 + fk;
#pragma unroll
      for (int f = 0; f < 4; f++)
        af[f]  = *(const bf16x8*)&lA[(wm + f * 16 + fr) * 64 + (kc ^ xorkey)];
#pragma unroll
      for (int f = 0; f < 4; f++)
        bfg[f] = *(const bf16x8*)&lB[(wn + f * 16 + fr) * 64 + (kc ^ xorkey)];
#pragma unroll
      for (int fm = 0; fm < 4; fm++)
#pragma unroll
        for (int fn = 0; fn < 4; fn++)
          acc[fm][fn] = __builtin_amdgcn_mfma_f32_16x16x32_bf16(af[fm], bfg[fn], acc[fm][fn], 0, 0, 0);
    }
  }

  if constexpr (EPI == EPI_DOT) {
    const float* bsl = bias + (long)z * 512;
    const float* wsl = dotW + (long)z * 512;
#pragma unroll
    for (int fm = 0; fm < 4; fm++) {
#pragma unroll
      for (int j = 0; j < 4; j++) {
        float p = 0.f;
#pragma unroll
        for (int fn = 0; fn < 4; fn++) {
          int col = n0 + wn + fn * 16 + fr;
          float v = acc[fm][fn][j] + bsl[col];
          v = lrelu(v);
          p += v * wsl[col];
        }
        p += __shfl_xor(p, 1); p += __shfl_xor(p, 2); p += __shfl_xor(p, 4); p += __shfl_xor(p, 8);
        if (fr == 0) {
          long row = (long)z * 8192 + (m0 + wm + fm * 16 + rbase + j);
          partial[row * 8 + blockIdx.y * 2 + (wv & 1)] = p;
        }
      }
    }
  } else {
#pragma unroll
    for (int fm = 0; fm < 4; fm++) {
#pragma unroll
      for (int fn = 0; fn < 4; fn++) {
        int col = n0 + wn + fn * 16 + fr;
        float badd = 0.f; bool act = false;
        if (col >= 256) { badd = bias[col - 256]; act = true; }
        us16* op = outB + (long)z * outSlice + (long)(m0 + wm + fm * 16 + rbase) * outRow + col;
#pragma unroll
        for (int j = 0; j < 4; j++) {
          float v = acc[fm][fn][j] + badd;
          if (act) v = lrelu(v);
          op[(long)j * outRow] = f2bf(v);
        }
      }
    }
  }
}

// ---------------------------------------------------------------------------
// Tier A2: 2-head fused KSV GEMM (proven round-10).
// ---------------------------------------------------------------------------
__global__ __launch_bounds__(256, 4)
void ksv2_k(const us16* __restrict__ enc, const us16* __restrict__ wkvst2,
            const float* __restrict__ bv2h, us16* __restrict__ ksv2)
{
  __shared__ us16 lA[128 * 64];
  __shared__ us16 lB[128 * 64];
  constexpr int KTOT = 512;
  const int tid = threadIdx.x;
  const int z = blockIdx.z;                    // agent
  const int el = blockIdx.y / 3;               // head within pair
  const int n0 = (blockIdx.y % 3) * 128;
  const int m0 = blockIdx.x * 128;
  const int wv = tid >> 6, lane = tid & 63;
  const int wm = (wv >> 1) * 64, wn = (wv & 1) * 64;
  const int fr = lane & 15, fk = (lane >> 4) * 8;
  const int rbase = (lane >> 4) * 4;
  const int xorkey = (fr & 7) << 3;

  f32x4 acc[4][4];
#pragma unroll
  for (int i = 0; i < 4; i++)
#pragma unroll
    for (int j = 0; j < 4; j++) acc[i][j] = f32x4{0.f, 0.f, 0.f, 0.f};

  const us16* abase = enc + (long)z * 8192 * 512 + (long)m0 * KTOT;
  const us16* bbase = wkvst2 + ((long)el * 384 + n0) * KTOT;

  for (int k0 = 0; k0 < KTOT; k0 += 64) {
    __syncthreads();
#pragma unroll
    for (int i = 0; i < 4; i++) {
      const int c = i * 256 + tid;
      const int r = c >> 3;
      const int col = ((c & 7) ^ (r & 7)) << 3;
      gload16(abase + (long)r * KTOT + (k0 + col), &lA[c * 8]);
    }
#pragma unroll
    for (int i = 0; i < 4; i++) {
      const int c = i * 256 + tid;
      const int r = c >> 3;
      const int col = ((c & 7) ^ (r & 7)) << 3;
      gload16(bbase + (long)r * KTOT + (k0 + col), &lB[c * 8]);
    }
    __syncthreads();

#pragma unroll
    for (int ks = 0; ks < 2; ks++) {
      bf16x8 af[4], bfg[4];
      const int kc = ks * 32 + fk;
#pragma unroll
      for (int f = 0; f < 4; f++)
        af[f]  = *(const bf16x8*)&lA[(wm + f * 16 + fr) * 64 + (kc ^ xorkey)];
#pragma unroll
      for (int f = 0; f < 4; f++)
        bfg[f] = *(const bf16x8*)&lB[(wn + f * 16 + fr) * 64 + (kc ^ xorkey)];
#pragma unroll
      for (int fm = 0; fm < 4; fm++)
#pragma unroll
        for (int fn = 0; fn < 4; fn++)
          acc[fm][fn] = __builtin_amdgcn_mfma_f32_16x16x32_bf16(af[fm], bfg[fn], acc[fm][fn], 0, 0, 0);
    }
  }

#pragma unroll
  for (int fm = 0; fm < 4; fm++) {
#pragma unroll
    for (int fn = 0; fn < 4; fn++) {
      int col = n0 + wn + fn * 16 + fr;          // 0..383 within head
      float badd = 0.f; bool act = false;
      if (col >= 256) { badd = bv2h[el * 128 + (col - 256)]; act = true; }
      us16* op = ksv2 + (long)(m0 + wm + fm * 16 + rbase) * 6144 + el * 3072 + z * 384 + col;
#pragma unroll
      for (int j = 0; j < 4; j++) {
        float v = acc[fm][fn][j] + badd;
        if (act) v = lrelu(v);
        op[(long)j * 6144] = f2bf(v);
      }
    }
  }
}

// ---------------------------------------------------------------------------
// Tier A4: 4-head fused KSV GEMM. grid (64, 12, 8): e = by/3, n0 = (by%3)*128.
// ---------------------------------------------------------------------------
__global__ __launch_bounds__(256, 4)
void ksv4_k(const us16* __restrict__ enc, const us16* __restrict__ wkvst,
            const float* __restrict__ bv, us16* __restrict__ ksv4)
{
  __shared__ us16 lA[128 * 64];
  __shared__ us16 lB[128 * 64];
  constexpr int KTOT = 512;
  const int tid = threadIdx.x;
  const int z = blockIdx.z;                    // agent
  const int e = blockIdx.y / 3;
  const int n0 = (blockIdx.y % 3) * 128;
  const int m0 = blockIdx.x * 128;
  const int wv = tid >> 6, lane = tid & 63;
  const int wm = (wv >> 1) * 64, wn = (wv & 1) * 64;
  const int fr = lane & 15, fk = (lane >> 4) * 8;
  const int rbase = (lane >> 4) * 4;
  const int xorkey = (fr & 7) << 3;

  f32x4 acc[4][4];
#pragma unroll
  for (int i = 0; i < 4; i++)
#pragma unroll
    for (int j = 0; j < 4; j++) acc[i][j] = f32x4{0.f, 0.f, 0.f, 0.f};

  const us16* abase = enc + (long)z * 8192 * 512 + (long)m0 * KTOT;
  const us16* bbase = wkvst + ((long)e * 384 + n0) * KTOT;

  for (int k0 = 0; k0 < KTOT; k0 += 64) {
    __syncthreads();
#pragma unroll
    for (int i = 0; i < 4; i++) {
      const int c = i * 256 + tid;
      const int r = c >> 3;
      const int col = ((c & 7) ^ (r & 7)) << 3;
      gload16(abase + (long)r * KTOT + (k0 + col), &lA[c * 8]);
    }
#pragma unroll
    for (int i = 0; i < 4; i++) {
      const int c = i * 256 + tid;
      const int r = c >> 3;
      const int col = ((c & 7) ^ (r & 7)) << 3;
      gload16(bbase + (long)r * KTOT + (k0 + col), &lB[c * 8]);
    }
    __syncthreads();

#pragma unroll
    for (int ks = 0; ks < 2; ks++) {
      bf16x8 af[4], bfg[4];
      const int kc = ks * 32 + fk;
#pragma unroll
      for (int f = 0; f < 4; f++)
        af[f]  = *(const bf16x8*)&lA[(wm + f * 16 + fr) * 64 + (kc ^ xorkey)];
#pragma unroll
      for (int f = 0; f < 4; f++)
        bfg[f] = *(const bf16x8*)&lB[(wn + f * 16 + fr) * 64 + (kc ^ xorkey)];
#pragma unroll
      for (int fm = 0; fm < 4; fm++)
#pragma unroll
        for (int fn = 0; fn < 4; fn++)
          acc[fm][fn] = __builtin_amdgcn_mfma_f32_16x16x32_bf16(af[fm], bfg[fn], acc[fm][fn], 0, 0, 0);
    }
  }

#pragma unroll
  for (int fm = 0; fm < 4; fm++) {
#pragma unroll
    for (int fn = 0; fn < 4; fn++) {
      int col = n0 + wn + fn * 16 + fr;          // 0..383 within head
      float badd = 0.f; bool act = false;
      if (col >= 256) { badd = bv[e * 128 + (col - 256)]; act = true; }
      us16* op = ksv4 + (long)(m0 + wm + fm * 16 + rbase) * 12288 + e * 3072 + z * 384 + col;
#pragma unroll
      for (int j = 0; j < 4; j++) {
        float v = acc[fm][fn][j] + badd;
        if (act) v = lrelu(v);
        op[(long)j * 12288] = f2bf(v);
      }
    }
  }
}

// ---------------------------------------------------------------------------
// Fused 2-MLP DOT GEMM (r14 proven; fallback). 8-slot PART.
// ---------------------------------------------------------------------------
__global__ __launch_bounds__(256, 4)
void dot2_k(const us16* __restrict__ encC, const us16* __restrict__ encV,
            const us16* __restrict__ other,
            const us16* __restrict__ wc1t, const us16* __restrict__ wv1t,
            const float* __restrict__ bc1, const float* __restrict__ bv1,
            const float* __restrict__ wc2, const float* __restrict__ wv2,
            float* __restrict__ partial)
{
  __shared__ us16 lA[128 * 64];
  __shared__ us16 lB[128 * 64];
  constexpr int KTOT = 1024;
  const int tid = threadIdx.x;
  const int zz = blockIdx.z;
  const int half = zz >> 3, z = zz & 7;
  const us16* Ap  = half ? encV : encC;
  const us16* Btp = half ? wv1t : wc1t;
  const float* bias = half ? bv1 : bc1;
  const float* dotW = half ? wv2 : wc2;
  const int m0 = blockIdx.x * 128;
  const int n0 = blockIdx.y * 128;
  const int wv = tid >> 6, lane = tid & 63;
  const int wm = (wv >> 1) * 64, wn = (wv & 1) * 64;
  const int fr = lane & 15, fk = (lane >> 4) * 8;
  const int rbase = (lane >> 4) * 4;
  const int xorkey = (fr & 7) << 3;

  f32x4 acc[4][4];
#pragma unroll
  for (int i = 0; i < 4; i++)
#pragma unroll
    for (int j = 0; j < 4; j++) acc[i][j] = f32x4{0.f, 0.f, 0.f, 0.f};

  const us16* bbase = Btp + (long)z * 512 * 1024 + (long)n0 * KTOT;
  const long aSlice = (long)8192 * 512;

  for (int k0 = 0; k0 < KTOT; k0 += 64) {
    __syncthreads();
#pragma unroll
    for (int i = 0; i < 4; i++) {
      const int c = i * 256 + tid;
      const int r = c >> 3;
      const int col = ((c & 7) ^ (r & 7)) << 3;
      const int kg = k0 + col;
      const us16* a = (kg < 512) ? Ap    + (long)z * aSlice + (long)(m0 + r) * 512 + kg
                                 : other + (long)z * aSlice + (long)(m0 + r) * 512 + (kg - 512);
      gload16(a, &lA[c * 8]);
    }
#pragma unroll
    for (int i = 0; i < 4; i++) {
      const int c = i * 256 + tid;
      const int r = c >> 3;
      const int col = ((c & 7) ^ (r & 7)) << 3;
      gload16(bbase + (long)r * KTOT + (k0 + col), &lB[c * 8]);
    }
    __syncthreads();

#pragma unroll
    for (int ks = 0; ks < 2; ks++) {
      bf16x8 af[4], bfg[4];
      const int kc = ks * 32 + fk;
#pragma unroll
      for (int f = 0; f < 4; f++)
        af[f]  = *(const bf16x8*)&lA[(wm + f * 16 + fr) * 64 + (kc ^ xorkey)];
#pragma unroll
      for (int f = 0; f < 4; f++)
        bfg[f] = *(const bf16x8*)&lB[(wn + f * 16 + fr) * 64 + (kc ^ xorkey)];
#pragma unroll
      for (int fm = 0; fm < 4; fm++)
#pragma unroll
        for (int fn = 0; fn < 4; fn++)
          acc[fm][fn] = __builtin_amdgcn_mfma_f32_16x16x32_bf16(af[fm], bfg[fn], acc[fm][fn], 0, 0, 0);
    }
  }

  const float* bsl = bias + (long)z * 512;
  const float* wsl = dotW + (long)z * 512;
#pragma unroll
  for (int fm = 0; fm < 4; fm++) {
#pragma unroll
    for (int j = 0; j < 4; j++) {
      float p = 0.f;
#pragma unroll
      for (int fn = 0; fn < 4; fn++) {
        int col = n0 + wn + fn * 16 + fr;
        float v = acc[fm][fn][j] + bsl[col];
        v = lrelu(v);
        p += v * wsl[col];
      }
      p += __shfl_xor(p, 1); p += __shfl_xor(p, 2); p += __shfl_xor(p, 4); p += __shfl_xor(p, 8);
      if (fr == 0) {
        long row = (long)half * 65536 + (long)z * 8192 + (m0 + wm + fm * 16 + rbase + j);
        partial[row * 8 + blockIdx.y * 2 + (wv & 1)] = p;
      }
    }
  }
}

// ---------------------------------------------------------------------------
// COUNTED-VMCNT DOT GEMM v2 (T4, 128 KiB): BM=256, BN=128, BK=64.
// LDS: A 3-buffered (a[i] = i*16384 elems, 32KB each), B 2-buffered
// (b[j] = 49152 + j*8192, 16KB each). Total 65536 elems = 131072 B.
// Per tile t: vmcnt(4) [A(t) issued 2 iters ago + B(t) 1 iter ago land;
// A(t+1)'s 4 loads stay in flight] -> barrier -> stage B(t+1), A(t+2)
// -> ds_read + 32 MFMA/wave -> barrier. 512 thr = 8 waves (2M x 4N).
// grid (32, 4, 16): zz<8 critic, else value. PART has 16 slots/row.
// ---------------------------------------------------------------------------
__global__ __launch_bounds__(512, 1)
void dotP_k(const us16* __restrict__ encC, const us16* __restrict__ encV,
            const us16* __restrict__ other,
            const us16* __restrict__ wc1t, const us16* __restrict__ wv1t,
            const float* __restrict__ bc1, const float* __restrict__ bv1,
            const float* __restrict__ wc2, const float* __restrict__ wv2,
            float* __restrict__ partial)
{
  extern __shared__ us16 lds[];   // 65536 elems = 131072 B
  constexpr int KTOT = 1024;
  const int tid = threadIdx.x;
  const int zz = blockIdx.z;
  const int half = zz >> 3, z = zz & 7;
  const us16* Ap  = half ? encV : encC;
  const us16* Btp = half ? wv1t : wc1t;
  const float* bias = half ? bv1 : bc1;
  const float* dotW = half ? wv2 : wc2;
  const int m0 = blockIdx.x * 256;
  const int n0 = blockIdx.y * 128;
  const int wv = tid >> 6, lane = tid & 63;
  const int wr = wv >> 2, wc = wv & 3;           // 2 x 4 waves
  const int wmBase = wr * 128, wnBase = wc * 32;
  const int fr = lane & 15, fk = (lane >> 4) * 8;
  const int rbase = (lane >> 4) * 4;
  const int srow = tid >> 3;                     // 0..63
  const int scol = ((tid & 7) ^ (srow & 7)) << 3;
  const long aSlice = (long)8192 * 512;
  const us16* bb = Btp + (long)z * 512 * 1024 + (long)n0 * KTOT;

  f32x4 acc[8][2];
#pragma unroll
  for (int i = 0; i < 8; i++)
#pragma unroll
    for (int j = 0; j < 2; j++) acc[i][j] = f32x4{0.f, 0.f, 0.f, 0.f};

  auto stageA = [&](int t, int buf) {   // 4 gloads (256 rows x 64 cols)
    us16* base = lds + buf * 16384;
    const int kg = t * 64 + scol;
#pragma unroll
    for (int g = 0; g < 4; g++) {
      const int r = g * 64 + srow;
      const us16* a = (kg < 512) ? Ap    + (long)z * aSlice + (long)(m0 + r) * 512 + kg
                                 : other + (long)z * aSlice + (long)(m0 + r) * 512 + (kg - 512);
      gload16(a, base + g * 4096 + tid * 8);
    }
  };
  auto stageB = [&](int t, int buf) {   // 2 gloads (128 rows x 64 cols)
    us16* base = lds + 49152 + buf * 8192;
    const int k0 = t * 64;
#pragma unroll
    for (int g = 0; g < 2; g++) {
      const int r = g * 64 + srow;
      gload16(bb + (long)r * KTOT + (k0 + scol), base + g * 4096 + tid * 8);
    }
  };

  constexpr int NT = KTOT / 64;  // 16
  // prologue (issue order matters for the counted wait): B0, A0, A1 = 10 loads
  stageB(0, 0);
  stageA(0, 0);
  stageA(1, 1);

  int aCur = 0, bCur = 0;
#pragma unroll 1
  for (int t = 0; t < NT; ++t) {
    // steady state outstanding: A(t)(4, oldest), B(t)(2), A(t+1)(4) = 10.
    // vmcnt(4) drains the 6 oldest = A(t)+B(t); A(t+1) stays in flight.
    if (t < NT - 1) asm volatile("s_waitcnt vmcnt(4)" ::: "memory");
    else            asm volatile("s_waitcnt vmcnt(0)" ::: "memory");
    __builtin_amdgcn_sched_barrier(0);
    __builtin_amdgcn_s_barrier();
    __builtin_amdgcn_sched_barrier(0);

    // stage next tiles (targets freed by iter t-1's end barrier)
    if (t + 1 < NT) stageB(t + 1, bCur ^ 1);
    const int aNxt = (aCur >= 1) ? aCur - 1 : 2;   // (aCur+2)%3
    if (t + 2 < NT) stageA(t + 2, aNxt);

    const us16* curA = lds + aCur * 16384;
    const us16* curB = lds + 49152 + bCur * 8192;

    bf16x8 bfg[2][2];
#pragma unroll
    for (int fn = 0; fn < 2; fn++)
#pragma unroll
      for (int ks = 0; ks < 2; ks++) {
        const int row = wnBase + fn * 16 + fr;
        bfg[fn][ks] = *(const bf16x8*)&curB[row * 64 + ((ks * 32 + fk) ^ ((row & 7) << 3))];
      }
    __builtin_amdgcn_s_setprio(1);
#pragma unroll
    for (int fm = 0; fm < 8; fm++) {
      const int row = wmBase + fm * 16 + fr;
      bf16x8 af0 = *(const bf16x8*)&curA[row * 64 + ((fk) ^ ((row & 7) << 3))];
      bf16x8 af1 = *(const bf16x8*)&curA[row * 64 + ((32 + fk) ^ ((row & 7) << 3))];
#pragma unroll
      for (int fn = 0; fn < 2; fn++) {
        acc[fm][fn] = __builtin_amdgcn_mfma_f32_16x16x32_bf16(af0, bfg[fn][0], acc[fm][fn], 0, 0, 0);
        acc[fm][fn] = __builtin_amdgcn_mfma_f32_16x16x32_bf16(af1, bfg[fn][1], acc[fm][fn], 0, 0, 0);
      }
    }
    __builtin_amdgcn_s_setprio(0);
    __builtin_amdgcn_s_barrier();              // readers of this tile done
    __builtin_amdgcn_sched_barrier(0);
    aCur = (aCur + 1 < 3) ? aCur + 1 : 0;
    bCur ^= 1;
  }

  // epilogue: hidden = lrelu(acc + b1[col]); partial += hidden * W2[col]
  const float* bsl = bias + (long)z * 512;
  const float* wsl = dotW + (long)z * 512;
#pragma unroll
  for (int fm = 0; fm < 8; fm++) {
#pragma unroll
    for (int j = 0; j < 4; j++) {
      float p = 0.f;
#pragma unroll
      for (int fn = 0; fn < 2; fn++) {
        int col = n0 + wnBase + fn * 16 + fr;
        float v = acc[fm][fn][j] + bsl[col];
        v = lrelu(v);
        p += v * wsl[col];
      }
      p += __shfl_xor(p, 1); p += __shfl_xor(p, 2); p += __shfl_xor(p, 4); p += __shfl_xor(p, 8);
      if (fr == 0) {
        long row = (long)half * 65536 + (long)z * 8192 + (m0 + wmBase + fm * 16 + rbase + j);
        partial[row * 16 + blockIdx.y * 4 + wc] = p;
      }
    }
  }
}

// ---------------------------------------------------------------------------
// Attention core + wrappers (Tier B / A2 / A4). launch_bounds (256,4).
// ---------------------------------------------------------------------------
DEVI void attn_core(const us16* __restrict__ src, us16* __restrict__ other,
                    int e, long b, int lane, us16* tbuf)
{
#pragma unroll
  for (int i = 0; i < 6; i++) {
    int c = i * 64 + lane;
    int r = c / 48, cc = c - r * 48;
    *(int4*)&tbuf[r * 392 + cc * 8] = *(const int4*)&src[c * 8];
  }
  __syncthreads();
  const int i = lane >> 3, j = lane & 7;
  const us16* selp = &tbuf[i * 392 + 128];
  const us16* keyp = &tbuf[j * 392];
  float acc = 0.f;
#pragma unroll
  for (int d = 0; d < 128; d += 8) {
    u16x8 s8 = *(const u16x8*)&selp[d];
    u16x8 k8 = *(const u16x8*)&keyp[d];
#pragma unroll
    for (int q = 0; q < 8; q++) acc += bf2f(s8[q]) * bf2f(k8[q]);
  }
  acc *= 0.088388347648318447f;
  float mx = acc;
  mx = fmaxf(mx, __shfl_xor(mx, 1)); mx = fmaxf(mx, __shfl_xor(mx, 2)); mx = fmaxf(mx, __shfl_xor(mx, 4));
  float ex = __expf(acc - mx);
  float sm = ex;
  sm += __shfl_xor(sm, 1); sm += __shfl_xor(sm, 2); sm += __shfl_xor(sm, 4);
  float wsm = ex / sm;
  float wj[8];
  const int ibase = lane & 56;
#pragma unroll
  for (int jj = 0; jj < 8; jj++) wj[jj] = __shfl(wsm, ibase + jj);
  const int dbase = (lane & 7) * 16;
  float o[16];
#pragma unroll
  for (int q = 0; q < 16; q++) o[q] = 0.f;
#pragma unroll
  for (int jj = 0; jj < 8; jj++) {
    u16x8 v0 = *(const u16x8*)&tbuf[jj * 392 + 256 + dbase];
    u16x8 v1 = *(const u16x8*)&tbuf[jj * 392 + 256 + dbase + 8];
    float wgt = wj[jj];
#pragma unroll
    for (int q = 0; q < 8; q++) { o[q] += wgt * bf2f(v0[q]); o[8 + q] += wgt * bf2f(v1[q]); }
  }
  u16x8 r0, r1;
#pragma unroll
  for (int q = 0; q < 8; q++) { r0[q] = f2bf(o[q]); r1[q] = f2bf(o[8 + q]); }
  us16* dst = other + ((long)i * 8192 + b) * 512 + e * 128 + dbase;
  *(u16x8*)&dst[0] = r0;
  *(u16x8*)&dst[8] = r1;
}

__global__ __launch_bounds__(256, 4)
void attn_k(const us16* __restrict__ ksv, us16* __restrict__ other, int e)
{
  __shared__ us16 t[4][8 * 392];
  const int wv = threadIdx.x >> 6, lane = threadIdx.x & 63;
  const long b = (long)blockIdx.x * 4 + wv;
  attn_core(ksv + b * 3072, other, e, b, lane, &t[wv][0]);
}

__global__ __launch_bounds__(256, 4)
void attn2_k(const us16* __restrict__ ksv2, us16* __restrict__ other, int ebase)
{
  __shared__ us16 t[4][8 * 392];
  const int wv = threadIdx.x >> 6, lane = threadIdx.x & 63;
  const long b = (long)blockIdx.x * 4 + wv;
  const int el = blockIdx.y;
  attn_core(ksv2 + b * 6144 + el * 3072, other, ebase + el, b, lane, &t[wv][0]);
}

__global__ __launch_bounds__(256, 4)
void attn4_k(const us16* __restrict__ ksv4, us16* __restrict__ other)
{
  __shared__ us16 t[4][8 * 392];
  const int wv = threadIdx.x >> 6, lane = threadIdx.x & 63;
  const long b = (long)blockIdx.x * 4 + wv;
  const int e = blockIdx.y;
  attn_core(ksv4 + b * 12288 + e * 3072, other, e, b, lane, &t[wv][0]);
}

// 8-slot reduce (dot2 path): r < 65536 -> q (bc2), else v (bv2).
__global__ void reduce2_k(const float* __restrict__ part, const float* __restrict__ b2c,
                          const float* __restrict__ b2v, float* __restrict__ out)
{
  int r = blockIdx.x * 256 + threadIdx.x;   // 0..131071
  const float4* p = (const float4*)(part + (long)r * 8);
  float4 a = p[0], b = p[1];
  float s = ((a.x + a.y) + (a.z + a.w)) + ((b.x + b.y) + (b.z + b.w));
  int agent = (r >> 13) & 7;
  out[r] = s + ((r < 65536) ? b2c[agent] : b2v[agent]);
}

// 16-slot reduce (dotP path).
__global__ void reduce16_k(const float* __restrict__ part, const float* __restrict__ b2c,
                           const float* __restrict__ b2v, float* __restrict__ out)
{
  int r = blockIdx.x * 256 + threadIdx.x;   // 0..131071
  const float4* p = (const float4*)(part + (long)r * 16);
  float s = 0.f;
#pragma unroll
  for (int i = 0; i < 4; i++) {
    float4 a = p[i];
    s += ((a.x + a.y) + (a.z + a.w));
  }
  int agent = (r >> 13) & 7;
  out[r] = s + ((r < 65536) ? b2c[agent] : b2v[agent]);
}

// ---------------------------------------------------------------------------
extern "C" void kernel_launch(void* const* d_in, const int* in_sizes, int n_in,
                              void* d_out, int out_size, void* d_ws, size_t ws_size,
                              hipStream_t stream)
{
  const float* states = (const float*)d_in[0];
  const float* actions= (const float*)d_in[1];
  const float* Ws  = (const float*)d_in[2];
  const float* bs  = (const float*)d_in[3];
  const float* Wsa = (const float*)d_in[4];
  const float* bsa = (const float*)d_in[5];
  const float* Wk  = (const float*)d_in[6];
  const float* Wsel= (const float*)d_in[7];
  const float* Wv  = (const float*)d_in[8];
  const float* bv  = (const float*)d_in[9];
  const float* Wc1 = (const float*)d_in[10];
  const float* bc1 = (const float*)d_in[11];
  const float* Wc2 = (const float*)d_in[12];
  const float* bc2 = (const float*)d_in[13];
  const float* Wv1 = (const float*)d_in[14];
  const float* bv1 = (const float*)d_in[15];
  const float* Wv2 = (const float*)d_in[16];
  const float* bv2 = (const float*)d_in[17];

  char* ws = (char*)d_ws;
  constexpr size_t OFF_WST   = 0;
  constexpr size_t OFF_WSAT  = OFF_WST   + (size_t)8 * 512 * 64 * 2;
  constexpr size_t OFF_WKVST = OFF_WSAT  + (size_t)8 * 512 * 96 * 2;
  constexpr size_t OFF_WC1T  = OFF_WKVST + (size_t)4 * 384 * 512 * 2;
  constexpr size_t OFF_WV1T  = OFF_WC1T  + (size_t)8 * 512 * 1024 * 2;
  constexpr size_t OFF_ENC   = OFF_WV1T  + (size_t)8 * 512 * 1024 * 2;
  constexpr size_t OFF_OTHER = OFF_ENC   + (size_t)8 * 8192 * 512 * 2;
  constexpr size_t OFF_KSV   = OFF_OTHER + (size_t)8 * 8192 * 512 * 2;
  // Tier B: KSV (one head) + PART (8-slot)
  constexpr size_t OFF_PARTB = OFF_KSV   + (size_t)8192 * 8 * 384 * 2;
  constexpr size_t NEED_B    = OFF_PARTB + (size_t)131072 * 8 * 4;
  // Tier A2: KSV2 (two heads); PART(8) + ENC2 aliased inside.
  constexpr size_t KSV2_BYTES = (size_t)8192 * 2 * 8 * 384 * 2;
  constexpr size_t NEED_A2    = OFF_KSV + KSV2_BYTES;               // ~254.5 MB
  // Tier A4: KSV4 (four heads); PART(16) + ENC2 aliased inside.
  constexpr size_t KSV4_BYTES = (size_t)8192 * 4 * 8 * 384 * 2;
  constexpr size_t NEED_A4    = OFF_KSV + KSV4_BYTES;               // ~355 MB
  constexpr size_t OFF_PARTA  = OFF_KSV;                            // 4.2 / 8.4 MB
  constexpr size_t OFF_ENC2_8 = OFF_KSV + (size_t)131072 * 8 * 4;   // dot2 layout
  constexpr size_t OFF_ENC2_16= OFF_KSV + (size_t)131072 * 16 * 4;  // dotP layout
  if (ws_size < NEED_B) return;
  const int tier = (ws_size >= NEED_A4) ? 2 : (ws_size >= NEED_A2) ? 1 : 0;

  us16* WST   = (us16*)(ws + OFF_WST);
  us16* WSAT  = (us16*)(ws + OFF_WSAT);
  us16* WKVST = (us16*)(ws + OFF_WKVST);
  us16* WC1T  = (us16*)(ws + OFF_WC1T);
  us16* WV1T  = (us16*)(ws + OFF_WV1T);
  us16* ENC   = (us16*)(ws + OFF_ENC);
  us16* OTHER = (us16*)(ws + OFF_OTHER);
  us16* KSV   = (us16*)(ws + OFF_KSV);
  float* PARTB= (float*)(ws + OFF_PARTB);
  float* PARTA= (float*)(ws + OFF_PARTA);

  // 128 KiB dynamic LDS opt-in (grantable per r7/r8 precedent).
  const bool pipeOK =
      hipFuncSetAttribute((const void*)dotP_k,
                          hipFuncAttributeMaxDynamicSharedMemorySize, 131072) == hipSuccess;
  us16* ENC2 = (us16*)(ws + (pipeOK ? OFF_ENC2_16 : OFF_ENC2_8));

  dim3 tb(32, 8);
  tconvSA_k<<<dim3(3, 16, 16), tb, 0, stream>>>(Ws, Wsa, WST, WSAT);
  tconv3_k <<<dim3(16, 4, 12), tb, 0, stream>>>(Wk, Wsel, Wv, WKVST);
  tconvC_k <<<dim3(32, 16, 16),tb, 0, stream>>>(Wc1, Wv1, WC1T, WV1T);

  // sa_enc = lrelu([states|actions] @ Wsa + bsa)  -> ENC (bf16)
  enc_gemm_k<ASRC_F32_CAT, 96><<<dim3(64, 4, 8), 256, 0, stream>>>(
      states, (long)8192 * 64, actions, (long)8192 * 16, WSAT, (long)512 * 96, bsa, 512,
      ENC, (long)8192 * 512, 512);

  if (tier == 2) {
    // all 4 heads: one KSV GEMM + one attention
    ksv4_k<<<dim3(64, 12, 8), 256, 0, stream>>>(ENC, WKVST, bv, KSV);
    attn4_k<<<dim3(2048, 4), 256, 0, stream>>>(KSV, OTHER);
    // s_enc -> ENC2 (aliased in the now-dead KSV4 region; stream-serial)
    enc_gemm_k<ASRC_F32, 64><<<dim3(64, 4, 8), 256, 0, stream>>>(
        states, (long)8192 * 64, nullptr, 0, WST, (long)512 * 64, bs, 512,
        ENC2, (long)8192 * 512, 512);
    if (pipeOK) {
      dotP_k<<<dim3(32, 4, 16), 512, 131072, stream>>>(
          ENC, ENC2, OTHER, WC1T, WV1T, bc1, bv1, Wc2, Wv2, PARTA);
      reduce16_k<<<dim3(512), 256, 0, stream>>>(PARTA, bc2, bv2, (float*)d_out);
    } else {
      dot2_k<<<dim3(64, 4, 16), 256, 0, stream>>>(
          ENC, ENC2, OTHER, WC1T, WV1T, bc1, bv1, Wc2, Wv2, PARTA);
      reduce2_k<<<dim3(512), 256, 0, stream>>>(PARTA, bc2, bv2, (float*)d_out);
    }
  } else if (tier == 1) {
    for (int h = 0; h < 2; h++) {
      ksv2_k<<<dim3(64, 6, 8), 256, 0, stream>>>(
          ENC, WKVST + (size_t)(h * 2) * 384 * 512, bv + h * 256, KSV);
      attn2_k<<<dim3(2048, 2), 256, 0, stream>>>(KSV, OTHER, h * 2);
    }
    us16* ENC2b = (us16*)(ws + OFF_ENC2_8);
    enc_gemm_k<ASRC_F32, 64><<<dim3(64, 4, 8), 256, 0, stream>>>(
        states, (long)8192 * 64, nullptr, 0, WST, (long)512 * 64, bs, 512,
        ENC2b, (long)8192 * 512, 512);
    dot2_k<<<dim3(64, 4, 16), 256, 0, stream>>>(
        ENC, ENC2b, OTHER, WC1T, WV1T, bc1, bv1, Wc2, Wv2, PARTA);
    reduce2_k<<<dim3(512), 256, 0, stream>>>(PARTA, bc2, bv2, (float*)d_out);
  } else {
    for (int e = 0; e < 4; e++) {
      gemm64_k<false, EPI_KSV, 512><<<dim3(64, 3, 8), 256, 0, stream>>>(
          ENC, (long)8192 * 512, nullptr, 0, WKVST + (size_t)e * 384 * 512, 0, bv + e * 128,
          KSV, 384, 3072, nullptr, nullptr);
      attn_k<<<dim3(2048), 256, 0, stream>>>(KSV, OTHER, e);
    }
    gemm64_k<true, EPI_DOT, 1024><<<dim3(64, 4, 8), 256, 0, stream>>>(
        ENC, (long)8192 * 512, OTHER, (long)8192 * 512, WC1T, (long)512 * 1024, bc1,
        nullptr, 0, 0, Wc2, PARTB);
    enc_gemm_k<ASRC_F32, 64><<<dim3(64, 4, 8), 256, 0, stream>>>(
        states, (long)8192 * 64, nullptr, 0, WST, (long)512 * 64, bs, 512,
        ENC, (long)8192 * 512, 512);
    gemm64_k<true, EPI_DOT, 1024><<<dim3(64, 4, 8), 256, 0, stream>>>(
        ENC, (long)8192 * 512, OTHER, (long)8192 * 512, WV1T, (long)512 * 1024, bv1,
        nullptr, 0, 0, Wv2, PARTB + (size_t)65536 * 8);
    reduce2_k<<<dim3(512), 256, 0, stream>>>(PARTB, bc2, bv2, (float*)d_out);
  }
}